// Round 17
// baseline (69.577 us; speedup 1.0000x reference)
//
#include <hip/hip_runtime.h>
#include <math.h>

#define NTOK 4096
#define C1 64
#define C2 256
#define CF 256
#define NH 8
#define HD 32
#define CFF 1024
#define EPSF 1e-5f
#define SPLIT 4
#define KVBLK 128
// Q pre-scale folded into Q projection: HD^-0.5 * log2(e)
#define QSCALE 0.25505654040876564f

using f32x4  = __attribute__((ext_vector_type(4))) float;
using bf16x8 = __attribute__((ext_vector_type(8))) short;
using u32x4  = __attribute__((ext_vector_type(4))) unsigned int;
typedef unsigned short ushort_t;

__device__ inline ushort_t f2bf(float x) {
    union { float f; unsigned int u; } v; v.f = x;
    unsigned int r = (v.u + 0x7FFFu + ((v.u >> 16) & 1u)) >> 16;
    return (ushort_t)r;
}
__device__ inline float bf2f(ushort_t u) {
    union { unsigned int i; float f; } v; v.i = ((unsigned int)u) << 16; return v.f;
}
__device__ inline unsigned int fbits(float x) {
    union { float f; unsigned int u; } v; v.f = x; return v.u;
}

// raw hardware exp2: single v_exp_f32, no OCML range/denorm fixup.
__device__ inline float exp2_raw(float x) {
#if __has_builtin(__builtin_amdgcn_exp2f)
    return __builtin_amdgcn_exp2f(x);
#else
    float r;
    asm("v_exp_f32 %0, %1" : "=v"(r) : "v"(x));
    return r;
#endif
}

// ---------- prep: weight fp32->bf16 convert (+tile/swizzle for tail weights) + transposes ----------
// Tail-weight tiled layout (Wo/Wres/W1/W2): tile = [256 outcols][64 k] = 32KB.
// tile index = (c>>8)*(K>>6) + (kk>>6); within tile, 16B unit for (c, kg=(kk>>3)&7)
// at ushort offset c*64 + ((kg ^ (c&7))<<3) + (kk&7).
__global__ __launch_bounds__(256) void prep_kernel(
    const float* __restrict__ Wq, const float* __restrict__ Wk,
    const float* __restrict__ Wv, const float* __restrict__ Wo,
    const float* __restrict__ Wres, const float* __restrict__ W1,
    const float* __restrict__ W2, const float* __restrict__ F_lidar,
    const float* __restrict__ F_cam,
    ushort_t* oWq, ushort_t* oWk, ushort_t* oWv, ushort_t* oWo,
    ushort_t* oWres, ushort_t* oW1, ushort_t* oW2,
    ushort_t* __restrict__ Flt, ushort_t* __restrict__ Fct) {
    __shared__ float tls[32][33];
    int b = blockIdx.x;
    if (b < 736) {
        const float* src; ushort_t* dst; int base, lgK; bool tiled;
        if      (b < 16)  { src = Wq;   dst = oWq;   base = b;       lgK = 6;  tiled = false; }
        else if (b < 80)  { src = Wk;   dst = oWk;   base = b - 16;  lgK = 8;  tiled = false; }
        else if (b < 144) { src = Wv;   dst = oWv;   base = b - 80;  lgK = 8;  tiled = false; }
        else if (b < 208) { src = Wo;   dst = oWo;   base = b - 144; lgK = 8;  tiled = true; }
        else if (b < 224) { src = Wres; dst = oWres; base = b - 208; lgK = 6;  tiled = true; }
        else if (b < 480) { src = W1;   dst = oW1;   base = b - 224; lgK = 8;  tiled = true; }
        else              { src = W2;   dst = oW2;   base = b - 480; lgK = 10; tiled = true; }
        const int i = base * 1024 + threadIdx.x * 4;
        const float4 v = *(const float4*)(src + i);
        ushort4 pk;
        pk.x = f2bf(v.x); pk.y = f2bf(v.y); pk.z = f2bf(v.z); pk.w = f2bf(v.w);
        if (!tiled) {
            *(ushort4*)(dst + i) = pk;
        } else {
            const int c  = i >> lgK;
            const int kk = i & ((1 << lgK) - 1);
            const int tau = (c >> 8) * (1 << (lgK - 6)) + (kk >> 6);
            const int dst4 = tau * 16384 + (c & 255) * 64
                           + (((((kk >> 3) & 7)) ^ (c & 7)) << 3) + (kk & 7);
            *(ushort4*)(dst + dst4) = pk;
        }
        return;
    }
    b -= 736;
    const float* src; ushort_t* dst; int C, c0, n0;
    if (b < 256) { src = F_lidar; dst = Flt; C = C1; c0 = (b & 1) * 32; n0 = (b >> 1) * 32; }
    else { b -= 256; src = F_cam; dst = Fct; C = C2; c0 = (b & 7) * 32; n0 = (b >> 3) * 32; }
    const int tx = threadIdx.x & 31, ty = threadIdx.x >> 5;
#pragma unroll
    for (int i = 0; i < 32; i += 8) tls[ty + i][tx] = src[(size_t)(c0 + ty + i) * NTOK + n0 + tx];
    __syncthreads();
#pragma unroll
    for (int i = 0; i < 32; i += 8) dst[(size_t)(n0 + ty + i) * C + c0 + tx] = f2bf(tls[tx][ty + i]);
}

// ---------- fused Q/K/V projections; K,V stored with fattn's LDS layouts baked in ----------
__global__ __launch_bounds__(256) void qkv_kernel(
    const ushort_t* __restrict__ Flt, const ushort_t* __restrict__ Fct,
    const ushort_t* __restrict__ Wqb, const ushort_t* __restrict__ Wkb,
    const ushort_t* __restrict__ Wvb,
    ushort_t* __restrict__ Qb, ushort_t* __restrict__ Kb, ushort_t* __restrict__ Vt) {
    const int z = blockIdx.z;
    const ushort_t* A = (z == 0) ? Flt : Fct;
    const ushort_t* W = (z == 0) ? Wqb : (z == 1) ? Wkb : Wvb;
    const int K = (z == 0) ? C1 : C2;

    const int tid = threadIdx.x;
    const int wid = tid >> 6, lane = tid & 63;
    const int g = lane >> 4, r = lane & 15;
    const int r0 = blockIdx.x * 128 + wid * 16;
    const int c0 = blockIdx.y * 64;

    f32x4 acc[2][4];
#pragma unroll
    for (int i = 0; i < 2; ++i)
#pragma unroll
        for (int t = 0; t < 4; ++t) acc[i][t] = (f32x4){0, 0, 0, 0};

    const ushort_t* ap0 = A + (size_t)(r0 + r) * K + (g << 3);
    const ushort_t* ap1 = ap0 + (size_t)64 * K;
    const ushort_t* wp = W + (size_t)(c0 + r) * K + (g << 3);
#pragma unroll 2
    for (int k0 = 0; k0 < K; k0 += 32) {
        const bf16x8 a0 = *(const bf16x8*)(ap0 + k0);
        const bf16x8 a1 = *(const bf16x8*)(ap1 + k0);
#pragma unroll
        for (int t = 0; t < 4; ++t) {
            const bf16x8 wf = *(const bf16x8*)(wp + (size_t)(t * 16) * K + k0);
            acc[0][t] = __builtin_amdgcn_mfma_f32_16x16x32_bf16(a0, wf, acc[0][t], 0, 0, 0);
            acc[1][t] = __builtin_amdgcn_mfma_f32_16x16x32_bf16(a1, wf, acc[1][t], 0, 0, 0);
        }
    }
    if (z == 0) {  // Q: linear, pre-scaled
#pragma unroll
        for (int i = 0; i < 2; ++i)
#pragma unroll
            for (int t = 0; t < 4; ++t) {
                const int col = c0 + 16 * t + r;
#pragma unroll
                for (int q = 0; q < 4; ++q)
                    Qb[(size_t)(r0 + i * 64 + 4 * g + q) * CF + col] = f2bf(acc[i][t][q] * QSCALE);
            }
    } else if (z == 1) {  // K: dim-group bits ^= (token>>1)&3 (LDS bank swizzle)
#pragma unroll
        for (int i = 0; i < 2; ++i)
#pragma unroll
            for (int t = 0; t < 4; ++t) {
                const int col = c0 + 16 * t + r;
#pragma unroll
                for (int q = 0; q < 4; ++q) {
                    const int tok = r0 + i * 64 + 4 * g + q;
                    const int cs = (col & ~31) | ((((col >> 3) & 3) ^ ((tok >> 1) & 3)) << 3) | (col & 7);
                    Kb[(size_t)tok * CF + cs] = f2bf(acc[i][t][q]);
                }
            }
    } else {  // V: unit layout u = c*32 + (d ^ (c&7)), byte j*2 within unit
#pragma unroll
        for (int i = 0; i < 2; ++i)
#pragma unroll
            for (int t = 0; t < 4; ++t) {
                const int dglob = c0 + 16 * t + r;
                const int hh = dglob >> 5, d = dglob & 31;
                const int tok0 = r0 + i * 64 + 4 * g;    // 4-aligned
                const int T = tok0 >> 7, tl = tok0 & 127;
                const int kc = tl >> 5, gp = (tl >> 2) & 3, jh = (tl >> 4) & 1;
                const int c = kc * 4 + gp;
                ushort4 pk;
                pk.x = f2bf(acc[i][t][0]); pk.y = f2bf(acc[i][t][1]);
                pk.z = f2bf(acc[i][t][2]); pk.w = f2bf(acc[i][t][3]);
                *(ushort4*)((char*)Vt + ((size_t)(hh * 32 + T) << 13)
                            + ((size_t)(c * 32 + (d ^ (c & 7))) << 4) + (jh << 3)) = pk;
            }
    }
}

// ---------- flash attention: 8 waves x 2 q-tiles (256 q/block), raw v_exp_f32, setprio ----------
__global__ __launch_bounds__(512, 4) void fattn_kernel(const ushort_t* __restrict__ Qb,
                                                       const ushort_t* __restrict__ Kb,
                                                       const ushort_t* __restrict__ Vt,
                                                       ushort_t* __restrict__ Opart,
                                                       float* __restrict__ Lst) {
    __shared__ ushort_t Ks[3][4096];   // 8 KB x3
    __shared__ ushort_t Vs[3][4096];   // 8 KB x3

    const int tid = threadIdx.x;
    const int wid = tid >> 6, lane = tid & 63;
    const int g = lane >> 4, r = lane & 15;
    const int bid = blockIdx.x;
    const int qb = bid & 15;
    const int sp = (bid >> 4) & (SPLIT - 1);
    const int h  = bid >> 6;
    const int n0 = qb * 256 + wid * 32;
    const int m_beg = sp * (NTOK / SPLIT);

    const bf16x8 qfA = *(const bf16x8*)(Qb + ((size_t)(n0 + r) << 8) + h * HD + (g << 3));
    const bf16x8 qfB = *(const bf16x8*)(Qb + ((size_t)(n0 + 16 + r) << 8) + h * HD + (g << 3));
    const bf16x8 onesf = {(short)0x3F80, (short)0x3F80, (short)0x3F80, (short)0x3F80,
                          (short)0x3F80, (short)0x3F80, (short)0x3F80, (short)0x3F80};

    const char* kb  = (const char*)Ks[0] + (r << 6) + ((g ^ ((r >> 1) & 3)) << 4);
    const char* vbg = (const char*)Vs[0] + (g << 9) + ((r & 8) << 4);
    const int slotbase = ((r & 7) ^ g) << 4;

    const int o = tid << 4;
    const char* ksrc = (const char*)Kb + (size_t)(m_beg + (o >> 6)) * 512 + (h << 6) + (o & 63);
    const char* vsrc = (const char*)Vt + ((size_t)(h * 32 + (m_beg >> 7)) << 13) + o;

    auto stage = [&](int bufs) {
        __builtin_amdgcn_global_load_lds(
            (const __attribute__((address_space(1))) unsigned int*)ksrc,
            (__attribute__((address_space(3))) unsigned int*)((char*)Ks[bufs] + (wid << 10)), 16, 0, 0);
        __builtin_amdgcn_global_load_lds(
            (const __attribute__((address_space(1))) unsigned int*)vsrc,
            (__attribute__((address_space(3))) unsigned int*)((char*)Vs[bufs] + (wid << 10)), 16, 0, 0);
        ksrc += KVBLK * 512;
        vsrc += 8192;
    };

    f32x4 accA0 = {0, 0, 0, 0}, accA1 = {0, 0, 0, 0}, laccA = {0, 0, 0, 0};
    f32x4 accB0 = {0, 0, 0, 0}, accB1 = {0, 0, 0, 0}, laccB = {0, 0, 0, 0};

    stage(0);
    stage(1);
    asm volatile("s_waitcnt vmcnt(2)" ::: "memory");
    __builtin_amdgcn_s_barrier();

    constexpr int NT = (NTOK / SPLIT) / KVBLK;  // 8
#pragma unroll
    for (int tt = 0; tt < NT; ++tt) {
        if (tt + 2 < NT) stage((tt + 2) % 3);
        const int bofs = (tt % 3) << 13;

        f32x4 sA[8], sB[8];
        __builtin_amdgcn_s_setprio(1);
#pragma unroll
        for (int t8 = 0; t8 < 8; ++t8) {
            const bf16x8 kf = *(const bf16x8*)(kb + bofs + (t8 << 10));
            sA[t8] = __builtin_amdgcn_mfma_f32_16x16x32_bf16(kf, qfA, (f32x4){0, 0, 0, 0}, 0, 0, 0);
            sB[t8] = __builtin_amdgcn_mfma_f32_16x16x32_bf16(kf, qfB, (f32x4){0, 0, 0, 0}, 0, 0, 0);
        }
        __builtin_amdgcn_s_setprio(0);
        u32x4 pkvA[4], pkvB[4];
#pragma unroll
        for (int t8 = 0; t8 < 8; ++t8) {
            const float a0 = exp2_raw(sA[t8][0]);
            const float a1 = exp2_raw(sA[t8][1]);
            const float a2 = exp2_raw(sA[t8][2]);
            const float a3 = exp2_raw(sA[t8][3]);
            pkvA[t8 >> 1][(t8 & 1) * 2]     = __builtin_amdgcn_perm(fbits(a1), fbits(a0), 0x07060302u);
            pkvA[t8 >> 1][(t8 & 1) * 2 + 1] = __builtin_amdgcn_perm(fbits(a3), fbits(a2), 0x07060302u);
        }
#pragma unroll
        for (int t8 = 0; t8 < 8; ++t8) {
            const float b0 = exp2_raw(sB[t8][0]);
            const float b1 = exp2_raw(sB[t8][1]);
            const float b2 = exp2_raw(sB[t8][2]);
            const float b3 = exp2_raw(sB[t8][3]);
            pkvB[t8 >> 1][(t8 & 1) * 2]     = __builtin_amdgcn_perm(fbits(b1), fbits(b0), 0x07060302u);
            pkvB[t8 >> 1][(t8 & 1) * 2 + 1] = __builtin_amdgcn_perm(fbits(b3), fbits(b2), 0x07060302u);
        }
        __builtin_amdgcn_s_setprio(1);
#pragma unroll
        for (int kc = 0; kc < 4; ++kc) {
            union { u32x4 u; bf16x8 b; } puA, puB;
            puA.u = pkvA[kc]; puB.u = pkvB[kc];
            const bf16x8 pfA = puA.b, pfB = puB.b;
            laccA = __builtin_amdgcn_mfma_f32_16x16x32_bf16(pfA, onesf, laccA, 0, 0, 0);
            laccB = __builtin_amdgcn_mfma_f32_16x16x32_bf16(pfB, onesf, laccB, 0, 0, 0);
            const char* va = vbg + bofs + (kc << 11) + (slotbase ^ ((kc & 1) << 6));
            const bf16x8 vf0 = *(const bf16x8*)(va);
            const bf16x8 vf1 = *(const bf16x8*)(va + 256);
            accA0 = __builtin_amdgcn_mfma_f32_16x16x32_bf16(pfA, vf0, accA0, 0, 0, 0);
            accB0 = __builtin_amdgcn_mfma_f32_16x16x32_bf16(pfB, vf0, accB0, 0, 0, 0);
            accA1 = __builtin_amdgcn_mfma_f32_16x16x32_bf16(pfA, vf1, accA1, 0, 0, 0);
            accB1 = __builtin_amdgcn_mfma_f32_16x16x32_bf16(pfB, vf1, accB1, 0, 0, 0);
        }
        __builtin_amdgcn_s_setprio(0);
        if (tt + 2 < NT) { asm volatile("s_waitcnt vmcnt(2)" ::: "memory"); }
        else             { asm volatile("s_waitcnt vmcnt(0)" ::: "memory"); }
        __builtin_amdgcn_s_barrier();
    }
    const size_t baseA = (size_t)(sp * NH + h) * NTOK + n0;
    const size_t baseB = baseA + 16;
    if (r == 0) {
        *(f32x4*)(Lst + baseA + 4 * g) = laccA;
        *(f32x4*)(Lst + baseB + 4 * g) = laccB;
    }
#pragma unroll
    for (int q = 0; q < 4; ++q) {
        const size_t rowbA = (baseA + 4 * g + q) * HD;
        Opart[rowbA + r]      = f2bf(accA0[q]);
        Opart[rowbA + 16 + r] = f2bf(accA1[q]);
        const size_t rowbB = (baseB + 4 * g + q) * HD;
        Opart[rowbB + r]      = f2bf(accB0[q]);
        Opart[rowbB + 16 + r] = f2bf(accB1[q]);
    }
}

// ---------- fused tail: ONE continuous 37-tile weight ring; all scalars pre-staged in LDS ----------
// 16 rows/block, 512 thr (8 waves, wave = 32 out-cols). Tile schedule: 0-3 Wo, 4 Wres,
// 5-20 W1, 21-36 W2. No VMEM ops mid-stream except ring stages -> exact vmcnt counting.
__global__ __launch_bounds__(512) void tail_kernel(
    const ushort_t* __restrict__ Opart, const float* __restrict__ Lst,
    const ushort_t* __restrict__ Wo,
    const ushort_t* __restrict__ Flt, const ushort_t* __restrict__ Wres,
    const float* __restrict__ g1, const float* __restrict__ bt1,
    const ushort_t* __restrict__ W1, const float* __restrict__ b1,
    const ushort_t* __restrict__ W2, const float* __restrict__ b2,
    const float* __restrict__ g2, const float* __restrict__ bt2,
    float* __restrict__ out) {
    __shared__ ushort_t Wb[3][16384];    // 96 KB weight-tile ring
    __shared__ ushort_t As[16][264];     // merged attention rows
    __shared__ ushort_t Xs[16][264];     // LN1 output (bf16)
    __shared__ ushort_t Hs[16][1032];    // FFN hidden
    __shared__ ushort_t Fs[16][72];      // Flt slice (bf16)
    __shared__ float Bias[2304];         // g1,bt1,b2,g2,bt2 (5x256) + b1 (1024)
    __shared__ float redS[8][16], redQ[8][16];
    const int tid = threadIdx.x;
    const int wid = tid >> 6, lane = tid & 63;
    const int g = lane >> 4, r = lane & 15;
    const int row0 = blockIdx.x * 16;
    const int cw = wid * 32;

    // lane weight-frag byte offsets within a staged tile
    const int wl00 = (cw + r) * 128 + ((g ^ (r & 7)) << 4);
    const int wl01 = wl00 + 2048;
    const int wl10 = (cw + r) * 128 + (((4 + g) ^ (r & 7)) << 4);
    const int wl11 = wl10 + 2048;

    auto stageW = [&](const ushort_t* src, int buf) {
        const char* s = (const char*)src + (tid << 4);
        char* d = (char*)&Wb[buf][0] + (tid << 4);
#pragma unroll
        for (int j = 0; j < 4; ++j) {
            __builtin_amdgcn_global_load_lds(
                (const __attribute__((address_space(1))) unsigned int*)(s + j * 8192),
                (__attribute__((address_space(3))) unsigned int*)(d + j * 8192), 16, 0, 0);
        }
    };
    auto wsrc = [&](int s) -> const ushort_t* {
        if (s < 4)  return Wo + (size_t)s * 16384;
        if (s == 4) return Wres;
        if (s < 21) return W1 + (size_t)(s - 5) * 16384;
        return W2 + (size_t)(s - 21) * 16384;
    };

    // ---- phase A: merge SPLIT partials + pre-stage biases & Flt slice into LDS ----
    {
        const int ri = tid >> 5;            // 0..15
        const int cc = (tid & 31) << 3;     // 0..248
        const int h  = cc >> 5, d0 = cc & 31;
        const int n  = row0 + ri;
        float L = 0.f;
#pragma unroll
        for (int s = 0; s < SPLIT; ++s) L += Lst[(size_t)(s * NH + h) * NTOK + n];
        const float invL = 1.f / L;
        float o[8] = {0.f, 0.f, 0.f, 0.f, 0.f, 0.f, 0.f, 0.f};
#pragma unroll
        for (int s = 0; s < SPLIT; ++s) {
            const ushort_t* p = Opart + ((size_t)(s * NH + h) * NTOK + n) * HD + d0;
            const ushort4 a = *(const ushort4*)p;
            const ushort4 b = *(const ushort4*)(p + 4);
            o[0] += bf2f(a.x); o[1] += bf2f(a.y); o[2] += bf2f(a.z); o[3] += bf2f(a.w);
            o[4] += bf2f(b.x); o[5] += bf2f(b.y); o[6] += bf2f(b.z); o[7] += bf2f(b.w);
        }
        ushort4 m0, m1;
        m0.x = f2bf(o[0] * invL); m0.y = f2bf(o[1] * invL);
        m0.z = f2bf(o[2] * invL); m0.w = f2bf(o[3] * invL);
        m1.x = f2bf(o[4] * invL); m1.y = f2bf(o[5] * invL);
        m1.z = f2bf(o[6] * invL); m1.w = f2bf(o[7] * invL);
        *(ushort4*)&As[ri][cc]     = m0;
        *(ushort4*)&As[ri][cc + 4] = m1;
        // Flt slice: 16 rows x 64 cols bf16
        *(ushort2*)&Fs[ri][(tid & 31) * 2] =
            *(const ushort2*)(Flt + (size_t)(row0 + ri) * C1 + (tid & 31) * 2);
        // biases
#pragma unroll
        for (int i5 = 0; i5 < 5; ++i5) {
            const int i = i5 * 512 + tid;
            if (i < 2304) {
                float v;
                if      (i < 256)  v = g1[i];
                else if (i < 512)  v = bt1[i - 256];
                else if (i < 768)  v = b2[i - 512];
                else if (i < 1024) v = g2[i - 768];
                else if (i < 1280) v = bt2[i - 1024];
                else               v = b1[i - 1280];
                Bias[i] = v;
            }
        }
    }
    __syncthreads();

    // ---- ring prologue ----
    stageW(wsrc(0), 0);
    stageW(wsrc(1), 1);
    asm volatile("s_waitcnt vmcnt(4)" ::: "memory");
    __builtin_amdgcn_s_barrier();

    // ---- phase B: tiles 0..4 (Wo x4 + Wres) ----
    f32x4 accB[2] = {{0, 0, 0, 0}, {0, 0, 0, 0}};
#pragma unroll
    for (int t = 0; t < 5; ++t) {
        stageW(wsrc(t + 2), (t + 2) % 3);
        const char* wb = (const char*)&Wb[t % 3][0];
        const bf16x8 w00 = *(const bf16x8*)(wb + wl00);
        const bf16x8 w01 = *(const bf16x8*)(wb + wl01);
        const bf16x8 w10 = *(const bf16x8*)(wb + wl10);
        const bf16x8 w11 = *(const bf16x8*)(wb + wl11);
        bf16x8 af0, af1;
        if (t < 4) {
            af0 = *(const bf16x8*)&As[r][t * 64 + (g << 3)];
            af1 = *(const bf16x8*)&As[r][t * 64 + 32 + (g << 3)];
        } else {
            af0 = *(const bf16x8*)&Fs[r][(g << 3)];
            af1 = *(const bf16x8*)&Fs[r][32 + (g << 3)];
        }
        accB[0] = __builtin_amdgcn_mfma_f32_16x16x32_bf16(af0, w00, accB[0], 0, 0, 0);
        accB[1] = __builtin_amdgcn_mfma_f32_16x16x32_bf16(af0, w01, accB[1], 0, 0, 0);
        accB[0] = __builtin_amdgcn_mfma_f32_16x16x32_bf16(af1, w10, accB[0], 0, 0, 0);
        accB[1] = __builtin_amdgcn_mfma_f32_16x16x32_bf16(af1, w11, accB[1], 0, 0, 0);
        asm volatile("s_waitcnt vmcnt(4)" ::: "memory");
        __builtin_amdgcn_s_barrier();
    }
    // ---- LN1; xv stays in registers as FFN2 residual ----
    f32x4 xv[2];
    {
        f32x4 sv, qv;
#pragma unroll
        for (int q = 0; q < 4; ++q) {
            float s = accB[0][q] + accB[1][q];
            float sq = fmaf(accB[0][q], accB[0][q], accB[1][q] * accB[1][q]);
            s += __shfl_xor(s, 1); s += __shfl_xor(s, 2); s += __shfl_xor(s, 4); s += __shfl_xor(s, 8);
            sq += __shfl_xor(sq, 1); sq += __shfl_xor(sq, 2); sq += __shfl_xor(sq, 4); sq += __shfl_xor(sq, 8);
            sv[q] = s; qv[q] = sq;
        }
        if (r == 0) { *(f32x4*)&redS[wid][4 * g] = sv; *(f32x4*)&redQ[wid][4 * g] = qv; }
        __syncthreads();
        f32x4 S = {0, 0, 0, 0}, SQ = {0, 0, 0, 0};
#pragma unroll
        for (int w = 0; w < 8; ++w) {
            S  += *(const f32x4*)&redS[w][4 * g];
            SQ += *(const f32x4*)&redQ[w][4 * g];
        }
        f32x4 mn4, rs4;
#pragma unroll
        for (int q = 0; q < 4; ++q) {
            mn4[q] = S[q] * (1.f / CF);
            rs4[q] = rsqrtf(fmaxf(SQ[q] * (1.f / CF) - mn4[q] * mn4[q], 0.f) + EPSF);
        }
#pragma unroll
        for (int t = 0; t < 2; ++t) {
            const int col = cw + 16 * t + r;
            const float gam = Bias[col], bet = Bias[256 + col];
#pragma unroll
            for (int q = 0; q < 4; ++q) {
                xv[t][q] = (accB[t][q] - mn4[q]) * rs4[q] * gam + bet;
                Xs[4 * g + q][col] = f2bf(xv[t][q]);
            }
        }
    }
    __syncthreads();

    // ---- phase C: tiles 5..20 (W1), swapped MFMA ----
    {
        f32x4 acc1[8];
#pragma unroll
        for (int t = 0; t < 8; ++t) acc1[t] = (f32x4){0, 0, 0, 0};
#pragma unroll
        for (int t = 5; t < 21; ++t) {
            stageW(wsrc(t + 2), (t + 2) % 3);
            const int tc = t - 5;
            const char* wb = (const char*)&Wb[t % 3][0];
            const bf16x8 w00 = *(const bf16x8*)(wb + wl00);
            const bf16x8 w01 = *(const bf16x8*)(wb + wl01);
            const bf16x8 w10 = *(const bf16x8*)(wb + wl10);
            const bf16x8 w11 = *(const bf16x8*)(wb + wl11);
            const bf16x8 af0 = *(const bf16x8*)&Xs[r][(tc & 3) * 64 + (g << 3)];
            const bf16x8 af1 = *(const bf16x8*)&Xs[r][(tc & 3) * 64 + 32 + (g << 3)];
            const int idx = (tc >> 2) * 2;
            acc1[idx]     = __builtin_amdgcn_mfma_f32_16x16x32_bf16(w00, af0, acc1[idx], 0, 0, 0);
            acc1[idx + 1] = __builtin_amdgcn_mfma_f32_16x16x32_bf16(w01, af0, acc1[idx + 1], 0, 0, 0);
            acc1[idx]     = __builtin_amdgcn_mfma_f32_16x16x32_bf16(w10, af1, acc1[idx], 0, 0, 0);
            acc1[idx + 1] = __builtin_amdgcn_mfma_f32_16x16x32_bf16(w11, af1, acc1[idx + 1], 0, 0, 0);
            asm volatile("s_waitcnt vmcnt(4)" ::: "memory");
            __builtin_amdgcn_s_barrier();
        }
        // write H (swapped layout: lane holds 4 consecutive H-cols of row r)
#pragma unroll
        for (int idx = 0; idx < 8; ++idx) {
            const int colb = (idx >> 1) * 256 + cw + 16 * (idx & 1) + 4 * g;
            const f32x4 bv = *(const f32x4*)&Bias[1280 + colb];
            ushort4 hw;
            hw.x = f2bf(fmaxf(acc1[idx][0] + bv[0], 0.f));
            hw.y = f2bf(fmaxf(acc1[idx][1] + bv[1], 0.f));
            hw.z = f2bf(fmaxf(acc1[idx][2] + bv[2], 0.f));
            hw.w = f2bf(fmaxf(acc1[idx][3] + bv[3], 0.f));
            *(ushort4*)&Hs[r][colb] = hw;
        }
    }
    __syncthreads();

    // ---- phase D: tiles 21..36 (W2, K=1024) ----
    f32x4 accD[2] = {{0, 0, 0, 0}, {0, 0, 0, 0}};
#pragma unroll
    for (int t = 21; t < 37; ++t) {
        if (t + 2 < 37) stageW(wsrc(t + 2), (t + 2) % 3);
        const int tc = t - 21;
        const char* wb = (const char*)&Wb[t % 3][0];
        const bf16x8 w00 = *(const bf16x8*)(wb + wl00);
        const bf16x8 w01 = *(const bf16x8*)(wb + wl01);
        const bf16x8 w10 = *(const bf16x8*)(wb + wl10);
        const bf16x8 w11 = *(const bf16x8*)(wb + wl11);
        const bf16x8 af0 = *(const bf16x8*)&Hs[r][tc * 64 + (g << 3)];
        const bf16x8 af1 = *(const bf16x8*)&Hs[r][tc * 64 + 32 + (g << 3)];
        accD[0] = __builtin_amdgcn_mfma_f32_16x16x32_bf16(af0, w00, accD[0], 0, 0, 0);
        accD[1] = __builtin_amdgcn_mfma_f32_16x16x32_bf16(af0, w01, accD[1], 0, 0, 0);
        accD[0] = __builtin_amdgcn_mfma_f32_16x16x32_bf16(af1, w10, accD[0], 0, 0, 0);
        accD[1] = __builtin_amdgcn_mfma_f32_16x16x32_bf16(af1, w11, accD[1], 0, 0, 0);
        if (t + 2 < 37) { asm volatile("s_waitcnt vmcnt(4)" ::: "memory"); }
        else            { asm volatile("s_waitcnt vmcnt(0)" ::: "memory"); }
        __builtin_amdgcn_s_barrier();
    }
    // ---- b2 + reg-residual + LN2 + transposed store ----
    {
#pragma unroll
        for (int t = 0; t < 2; ++t) {
            const float bb = Bias[512 + cw + 16 * t + r];
#pragma unroll
            for (int q = 0; q < 4; ++q) accD[t][q] += bb + xv[t][q];
        }
        f32x4 sv, qv;
#pragma unroll
        for (int q = 0; q < 4; ++q) {
            float s = accD[0][q] + accD[1][q];
            float sq = fmaf(accD[0][q], accD[0][q], accD[1][q] * accD[1][q]);
            s += __shfl_xor(s, 1); s += __shfl_xor(s, 2); s += __shfl_xor(s, 4); s += __shfl_xor(s, 8);
            sq += __shfl_xor(sq, 1); sq += __shfl_xor(sq, 2); sq += __shfl_xor(sq, 4); sq += __shfl_xor(sq, 8);
            sv[q] = s; qv[q] = sq;
        }
        if (r == 0) { *(f32x4*)&redS[wid][4 * g] = sv; *(f32x4*)&redQ[wid][4 * g] = qv; }
        __syncthreads();
        f32x4 S = {0, 0, 0, 0}, SQ = {0, 0, 0, 0};
#pragma unroll
        for (int w = 0; w < 8; ++w) {
            S  += *(const f32x4*)&redS[w][4 * g];
            SQ += *(const f32x4*)&redQ[w][4 * g];
        }
        f32x4 mn4, rs4;
#pragma unroll
        for (int q = 0; q < 4; ++q) {
            mn4[q] = S[q] * (1.f / CF);
            rs4[q] = rsqrtf(fmaxf(SQ[q] * (1.f / CF) - mn4[q] * mn4[q], 0.f) + EPSF);
        }
#pragma unroll
        for (int t = 0; t < 2; ++t) {
            const int col = cw + 16 * t + r;
            const float gam = Bias[768 + col], bet = Bias[1024 + col];
            f32x4 ov;
#pragma unroll
            for (int q = 0; q < 4; ++q)
                ov[q] = (accD[t][q] - mn4[q]) * rs4[q] * gam + bet;
            *(f32x4*)(out + (size_t)col * NTOK + row0 + 4 * g) = ov;
        }
    }
}

extern "C" void kernel_launch(void* const* d_in, const int* in_sizes, int n_in,
                              void* d_out, int out_size, void* d_ws, size_t ws_size,
                              hipStream_t stream) {
    const float* F_lidar = (const float*)d_in[0];
    const float* F_cam   = (const float*)d_in[1];
    const float* Wq      = (const float*)d_in[2];
    const float* Wk      = (const float*)d_in[3];
    const float* Wv      = (const float*)d_in[4];
    const float* Wo      = (const float*)d_in[5];
    const float* Wres    = (const float*)d_in[6];
    const float* ln1_g   = (const float*)d_in[7];
    const float* ln1_b   = (const float*)d_in[8];
    const float* ln2_g   = (const float*)d_in[9];
    const float* ln2_b   = (const float*)d_in[10];
    const float* W1      = (const float*)d_in[11];
    const float* b1      = (const float*)d_in[12];
    const float* W2      = (const float*)d_in[13];
    const float* b2      = (const float*)d_in[14];
    float* out = (float*)d_out;
    char* ws = (char*)d_ws;

    const size_t KB = 1024, MB = 1024 * 1024;
    ushort_t* Wq_b   = (ushort_t*)(ws + 0);
    ushort_t* Wk_b   = (ushort_t*)(ws + 32 * KB);
    ushort_t* Wv_b   = (ushort_t*)(ws + 160 * KB);
    ushort_t* Wo_b   = (ushort_t*)(ws + 288 * KB);
    ushort_t* Wres_b = (ushort_t*)(ws + 416 * KB);
    ushort_t* W1_b   = (ushort_t*)(ws + 448 * KB);
    ushort_t* W2_b   = (ushort_t*)(ws + 960 * KB);
    ushort_t* Flt    = (ushort_t*)(ws + 1536 * KB);   // bf16 [4096][64]
    ushort_t* Fct    = (ushort_t*)(ws + 2 * MB);      // bf16 [4096][256]
    ushort_t* Qb     = (ushort_t*)(ws + 4 * MB);      // 2 MB (pre-scaled)
    ushort_t* Kb     = (ushort_t*)(ws + 6 * MB);      // 2 MB (bank-swizzled dims)
    ushort_t* Vt     = (ushort_t*)(ws + 8 * MB);      // 2 MB (unit layout per head/tile)
    ushort_t* Opart  = (ushort_t*)(ws + 12 * MB);     // 8 MB bf16 [4][8][4096][32]
    float*    Lst    = (float*)(ws + 20 * MB);        // 512 KB

    prep_kernel<<<2016, 256, 0, stream>>>(Wq, Wk, Wv, Wo, Wres, W1, W2, F_lidar, F_cam,
                                          Wq_b, Wk_b, Wv_b, Wo_b, Wres_b, W1_b, W2_b, Flt, Fct);
    qkv_kernel<<<dim3(NTOK / 128, CF / 64, 3), 256, 0, stream>>>(Flt, Fct, Wq_b, Wk_b, Wv_b, Qb, Kb, Vt);
    fattn_kernel<<<NH * SPLIT * (NTOK / 256), 512, 0, stream>>>(Qb, Kb, Vt, Opart, Lst);
    tail_kernel<<<NTOK / 16, 512, 0, stream>>>(Opart, Lst, Wo_b, Flt, Wres_b, ln1_g, ln1_b,
                                               W1_b, b1, W2_b, b2, ln2_g, ln2_b, out);
}

// Round 18
// 63.064 us; speedup vs baseline: 1.1033x; 1.1033x over previous
//
#include <hip/hip_runtime.h>
#include <math.h>

#define NTOK 4096
#define C1 64
#define C2 256
#define CF 256
#define NH 8
#define HD 32
#define CFF 1024
#define EPSF 1e-5f
#define SPLIT 4
#define KVBLK 128
// Q pre-scale folded into Q projection: HD^-0.5 * log2(e)
#define QSCALE 0.25505654040876564f

using f32x4  = __attribute__((ext_vector_type(4))) float;
using bf16x8 = __attribute__((ext_vector_type(8))) short;
using u32x4  = __attribute__((ext_vector_type(4))) unsigned int;
typedef unsigned short ushort_t;

__device__ inline ushort_t f2bf(float x) {
    union { float f; unsigned int u; } v; v.f = x;
    unsigned int r = (v.u + 0x7FFFu + ((v.u >> 16) & 1u)) >> 16;
    return (ushort_t)r;
}
__device__ inline float bf2f(ushort_t u) {
    union { unsigned int i; float f; } v; v.i = ((unsigned int)u) << 16; return v.f;
}
__device__ inline unsigned int fbits(float x) {
    union { float f; unsigned int u; } v; v.f = x; return v.u;
}

// raw hardware exp2: single v_exp_f32, no OCML range/denorm fixup.
__device__ inline float exp2_raw(float x) {
#if __has_builtin(__builtin_amdgcn_exp2f)
    return __builtin_amdgcn_exp2f(x);
#else
    float r;
    asm("v_exp_f32 %0, %1" : "=v"(r) : "v"(x));
    return r;
#endif
}

// ---------- prep: weight fp32->bf16 convert (+tile/swizzle for tail weights) + transposes ----------
// Tail-weight tiled layout (Wo/Wres/W1/W2): tile = [256 outcols][64 k] = 32KB.
// tile index = (c>>8)*(K>>6) + (kk>>6); within tile, 16B unit for (c, kg=(kk>>3)&7)
// at ushort offset c*64 + ((kg ^ (c&7))<<3) + (kk&7).
__global__ __launch_bounds__(256) void prep_kernel(
    const float* __restrict__ Wq, const float* __restrict__ Wk,
    const float* __restrict__ Wv, const float* __restrict__ Wo,
    const float* __restrict__ Wres, const float* __restrict__ W1,
    const float* __restrict__ W2, const float* __restrict__ F_lidar,
    const float* __restrict__ F_cam,
    ushort_t* oWq, ushort_t* oWk, ushort_t* oWv, ushort_t* oWo,
    ushort_t* oWres, ushort_t* oW1, ushort_t* oW2,
    ushort_t* __restrict__ Flt, ushort_t* __restrict__ Fct) {
    __shared__ float tls[32][33];
    int b = blockIdx.x;
    if (b < 736) {
        const float* src; ushort_t* dst; int base, lgK; bool tiled;
        if      (b < 16)  { src = Wq;   dst = oWq;   base = b;       lgK = 6;  tiled = false; }
        else if (b < 80)  { src = Wk;   dst = oWk;   base = b - 16;  lgK = 8;  tiled = false; }
        else if (b < 144) { src = Wv;   dst = oWv;   base = b - 80;  lgK = 8;  tiled = false; }
        else if (b < 208) { src = Wo;   dst = oWo;   base = b - 144; lgK = 8;  tiled = true; }
        else if (b < 224) { src = Wres; dst = oWres; base = b - 208; lgK = 6;  tiled = true; }
        else if (b < 480) { src = W1;   dst = oW1;   base = b - 224; lgK = 8;  tiled = true; }
        else              { src = W2;   dst = oW2;   base = b - 480; lgK = 10; tiled = true; }
        const int i = base * 1024 + threadIdx.x * 4;
        const float4 v = *(const float4*)(src + i);
        ushort4 pk;
        pk.x = f2bf(v.x); pk.y = f2bf(v.y); pk.z = f2bf(v.z); pk.w = f2bf(v.w);
        if (!tiled) {
            *(ushort4*)(dst + i) = pk;
        } else {
            const int c  = i >> lgK;
            const int kk = i & ((1 << lgK) - 1);
            const int tau = (c >> 8) * (1 << (lgK - 6)) + (kk >> 6);
            const int dst4 = tau * 16384 + (c & 255) * 64
                           + (((((kk >> 3) & 7)) ^ (c & 7)) << 3) + (kk & 7);
            *(ushort4*)(dst + dst4) = pk;
        }
        return;
    }
    b -= 736;
    const float* src; ushort_t* dst; int C, c0, n0;
    if (b < 256) { src = F_lidar; dst = Flt; C = C1; c0 = (b & 1) * 32; n0 = (b >> 1) * 32; }
    else { b -= 256; src = F_cam; dst = Fct; C = C2; c0 = (b & 7) * 32; n0 = (b >> 3) * 32; }
    const int tx = threadIdx.x & 31, ty = threadIdx.x >> 5;
#pragma unroll
    for (int i = 0; i < 32; i += 8) tls[ty + i][tx] = src[(size_t)(c0 + ty + i) * NTOK + n0 + tx];
    __syncthreads();
#pragma unroll
    for (int i = 0; i < 32; i += 8) dst[(size_t)(n0 + ty + i) * C + c0 + tx] = f2bf(tls[tx][ty + i]);
}

// ---------- fused Q/K/V projections; K,V stored with fattn's LDS layouts baked in ----------
__global__ __launch_bounds__(256) void qkv_kernel(
    const ushort_t* __restrict__ Flt, const ushort_t* __restrict__ Fct,
    const ushort_t* __restrict__ Wqb, const ushort_t* __restrict__ Wkb,
    const ushort_t* __restrict__ Wvb,
    ushort_t* __restrict__ Qb, ushort_t* __restrict__ Kb, ushort_t* __restrict__ Vt) {
    const int z = blockIdx.z;
    const ushort_t* A = (z == 0) ? Flt : Fct;
    const ushort_t* W = (z == 0) ? Wqb : (z == 1) ? Wkb : Wvb;
    const int K = (z == 0) ? C1 : C2;

    const int tid = threadIdx.x;
    const int wid = tid >> 6, lane = tid & 63;
    const int g = lane >> 4, r = lane & 15;
    const int r0 = blockIdx.x * 128 + wid * 16;
    const int c0 = blockIdx.y * 64;

    f32x4 acc[2][4];
#pragma unroll
    for (int i = 0; i < 2; ++i)
#pragma unroll
        for (int t = 0; t < 4; ++t) acc[i][t] = (f32x4){0, 0, 0, 0};

    const ushort_t* ap0 = A + (size_t)(r0 + r) * K + (g << 3);
    const ushort_t* ap1 = ap0 + (size_t)64 * K;
    const ushort_t* wp = W + (size_t)(c0 + r) * K + (g << 3);
#pragma unroll 2
    for (int k0 = 0; k0 < K; k0 += 32) {
        const bf16x8 a0 = *(const bf16x8*)(ap0 + k0);
        const bf16x8 a1 = *(const bf16x8*)(ap1 + k0);
#pragma unroll
        for (int t = 0; t < 4; ++t) {
            const bf16x8 wf = *(const bf16x8*)(wp + (size_t)(t * 16) * K + k0);
            acc[0][t] = __builtin_amdgcn_mfma_f32_16x16x32_bf16(a0, wf, acc[0][t], 0, 0, 0);
            acc[1][t] = __builtin_amdgcn_mfma_f32_16x16x32_bf16(a1, wf, acc[1][t], 0, 0, 0);
        }
    }
    if (z == 0) {  // Q: linear, pre-scaled
#pragma unroll
        for (int i = 0; i < 2; ++i)
#pragma unroll
            for (int t = 0; t < 4; ++t) {
                const int col = c0 + 16 * t + r;
#pragma unroll
                for (int q = 0; q < 4; ++q)
                    Qb[(size_t)(r0 + i * 64 + 4 * g + q) * CF + col] = f2bf(acc[i][t][q] * QSCALE);
            }
    } else if (z == 1) {  // K: dim-group bits ^= (token>>1)&3 (LDS bank swizzle)
#pragma unroll
        for (int i = 0; i < 2; ++i)
#pragma unroll
            for (int t = 0; t < 4; ++t) {
                const int col = c0 + 16 * t + r;
#pragma unroll
                for (int q = 0; q < 4; ++q) {
                    const int tok = r0 + i * 64 + 4 * g + q;
                    const int cs = (col & ~31) | ((((col >> 3) & 3) ^ ((tok >> 1) & 3)) << 3) | (col & 7);
                    Kb[(size_t)tok * CF + cs] = f2bf(acc[i][t][q]);
                }
            }
    } else {  // V: unit layout u = c*32 + (d ^ (c&7)), byte j*2 within unit
#pragma unroll
        for (int i = 0; i < 2; ++i)
#pragma unroll
            for (int t = 0; t < 4; ++t) {
                const int dglob = c0 + 16 * t + r;
                const int hh = dglob >> 5, d = dglob & 31;
                const int tok0 = r0 + i * 64 + 4 * g;    // 4-aligned
                const int T = tok0 >> 7, tl = tok0 & 127;
                const int kc = tl >> 5, gp = (tl >> 2) & 3, jh = (tl >> 4) & 1;
                const int c = kc * 4 + gp;
                ushort4 pk;
                pk.x = f2bf(acc[i][t][0]); pk.y = f2bf(acc[i][t][1]);
                pk.z = f2bf(acc[i][t][2]); pk.w = f2bf(acc[i][t][3]);
                *(ushort4*)((char*)Vt + ((size_t)(hh * 32 + T) << 13)
                            + ((size_t)(c * 32 + (d ^ (c & 7))) << 4) + (jh << 3)) = pk;
            }
    }
}

// ---------- flash attention: 8 waves x 2 q-tiles (256 q/block), raw v_exp_f32 ----------
__global__ __launch_bounds__(512, 4) void fattn_kernel(const ushort_t* __restrict__ Qb,
                                                       const ushort_t* __restrict__ Kb,
                                                       const ushort_t* __restrict__ Vt,
                                                       ushort_t* __restrict__ Opart,
                                                       float* __restrict__ Lst) {
    __shared__ ushort_t Ks[3][4096];   // 8 KB x3
    __shared__ ushort_t Vs[3][4096];   // 8 KB x3

    const int tid = threadIdx.x;
    const int wid = tid >> 6, lane = tid & 63;
    const int g = lane >> 4, r = lane & 15;
    const int bid = blockIdx.x;
    const int qb = bid & 15;
    const int sp = (bid >> 4) & (SPLIT - 1);
    const int h  = bid >> 6;
    const int n0 = qb * 256 + wid * 32;
    const int m_beg = sp * (NTOK / SPLIT);

    const bf16x8 qfA = *(const bf16x8*)(Qb + ((size_t)(n0 + r) << 8) + h * HD + (g << 3));
    const bf16x8 qfB = *(const bf16x8*)(Qb + ((size_t)(n0 + 16 + r) << 8) + h * HD + (g << 3));
    const bf16x8 onesf = {(short)0x3F80, (short)0x3F80, (short)0x3F80, (short)0x3F80,
                          (short)0x3F80, (short)0x3F80, (short)0x3F80, (short)0x3F80};

    const char* kb  = (const char*)Ks[0] + (r << 6) + ((g ^ ((r >> 1) & 3)) << 4);
    const char* vbg = (const char*)Vs[0] + (g << 9) + ((r & 8) << 4);
    const int slotbase = ((r & 7) ^ g) << 4;

    const int o = tid << 4;
    const char* ksrc = (const char*)Kb + (size_t)(m_beg + (o >> 6)) * 512 + (h << 6) + (o & 63);
    const char* vsrc = (const char*)Vt + ((size_t)(h * 32 + (m_beg >> 7)) << 13) + o;

    auto stage = [&](int bufs) {
        __builtin_amdgcn_global_load_lds(
            (const __attribute__((address_space(1))) unsigned int*)ksrc,
            (__attribute__((address_space(3))) unsigned int*)((char*)Ks[bufs] + (wid << 10)), 16, 0, 0);
        __builtin_amdgcn_global_load_lds(
            (const __attribute__((address_space(1))) unsigned int*)vsrc,
            (__attribute__((address_space(3))) unsigned int*)((char*)Vs[bufs] + (wid << 10)), 16, 0, 0);
        ksrc += KVBLK * 512;
        vsrc += 8192;
    };

    f32x4 accA0 = {0, 0, 0, 0}, accA1 = {0, 0, 0, 0}, laccA = {0, 0, 0, 0};
    f32x4 accB0 = {0, 0, 0, 0}, accB1 = {0, 0, 0, 0}, laccB = {0, 0, 0, 0};

    stage(0);
    stage(1);
    asm volatile("s_waitcnt vmcnt(2)" ::: "memory");
    __builtin_amdgcn_s_barrier();

    constexpr int NT = (NTOK / SPLIT) / KVBLK;  // 8
#pragma unroll
    for (int tt = 0; tt < NT; ++tt) {
        if (tt + 2 < NT) stage((tt + 2) % 3);
        const int bofs = (tt % 3) << 13;

        f32x4 sA[8], sB[8];
#pragma unroll
        for (int t8 = 0; t8 < 8; ++t8) {
            const bf16x8 kf = *(const bf16x8*)(kb + bofs + (t8 << 10));
            sA[t8] = __builtin_amdgcn_mfma_f32_16x16x32_bf16(kf, qfA, (f32x4){0, 0, 0, 0}, 0, 0, 0);
            sB[t8] = __builtin_amdgcn_mfma_f32_16x16x32_bf16(kf, qfB, (f32x4){0, 0, 0, 0}, 0, 0, 0);
        }
        u32x4 pkvA[4], pkvB[4];
#pragma unroll
        for (int t8 = 0; t8 < 8; ++t8) {
            const float a0 = exp2_raw(sA[t8][0]);
            const float a1 = exp2_raw(sA[t8][1]);
            const float a2 = exp2_raw(sA[t8][2]);
            const float a3 = exp2_raw(sA[t8][3]);
            pkvA[t8 >> 1][(t8 & 1) * 2]     = __builtin_amdgcn_perm(fbits(a1), fbits(a0), 0x07060302u);
            pkvA[t8 >> 1][(t8 & 1) * 2 + 1] = __builtin_amdgcn_perm(fbits(a3), fbits(a2), 0x07060302u);
        }
#pragma unroll
        for (int t8 = 0; t8 < 8; ++t8) {
            const float b0 = exp2_raw(sB[t8][0]);
            const float b1 = exp2_raw(sB[t8][1]);
            const float b2 = exp2_raw(sB[t8][2]);
            const float b3 = exp2_raw(sB[t8][3]);
            pkvB[t8 >> 1][(t8 & 1) * 2]     = __builtin_amdgcn_perm(fbits(b1), fbits(b0), 0x07060302u);
            pkvB[t8 >> 1][(t8 & 1) * 2 + 1] = __builtin_amdgcn_perm(fbits(b3), fbits(b2), 0x07060302u);
        }
#pragma unroll
        for (int kc = 0; kc < 4; ++kc) {
            union { u32x4 u; bf16x8 b; } puA, puB;
            puA.u = pkvA[kc]; puB.u = pkvB[kc];
            const bf16x8 pfA = puA.b, pfB = puB.b;
            laccA = __builtin_amdgcn_mfma_f32_16x16x32_bf16(pfA, onesf, laccA, 0, 0, 0);
            laccB = __builtin_amdgcn_mfma_f32_16x16x32_bf16(pfB, onesf, laccB, 0, 0, 0);
            const char* va = vbg + bofs + (kc << 11) + (slotbase ^ ((kc & 1) << 6));
            const bf16x8 vf0 = *(const bf16x8*)(va);
            const bf16x8 vf1 = *(const bf16x8*)(va + 256);
            accA0 = __builtin_amdgcn_mfma_f32_16x16x32_bf16(pfA, vf0, accA0, 0, 0, 0);
            accB0 = __builtin_amdgcn_mfma_f32_16x16x32_bf16(pfB, vf0, accB0, 0, 0, 0);
            accA1 = __builtin_amdgcn_mfma_f32_16x16x32_bf16(pfA, vf1, accA1, 0, 0, 0);
            accB1 = __builtin_amdgcn_mfma_f32_16x16x32_bf16(pfB, vf1, accB1, 0, 0, 0);
        }
        if (tt + 2 < NT) { asm volatile("s_waitcnt vmcnt(2)" ::: "memory"); }
        else             { asm volatile("s_waitcnt vmcnt(0)" ::: "memory"); }
        __builtin_amdgcn_s_barrier();
    }
    const size_t baseA = (size_t)(sp * NH + h) * NTOK + n0;
    const size_t baseB = baseA + 16;
    if (r == 0) {
        *(f32x4*)(Lst + baseA + 4 * g) = laccA;
        *(f32x4*)(Lst + baseB + 4 * g) = laccB;
    }
#pragma unroll
    for (int q = 0; q < 4; ++q) {
        const size_t rowbA = (baseA + 4 * g + q) * HD;
        Opart[rowbA + r]      = f2bf(accA0[q]);
        Opart[rowbA + 16 + r] = f2bf(accA1[q]);
        const size_t rowbB = (baseB + 4 * g + q) * HD;
        Opart[rowbB + r]      = f2bf(accB0[q]);
        Opart[rowbB + 16 + r] = f2bf(accB1[q]);
    }
}

// ---------- fused tail: PER-WAVE weight pipeline (each wave stages/reads only its own
// 4KB row-slice of every tile -> tile readiness is the wave's own vmcnt, NO per-tile
// barriers). 37-tile schedule: 0-3 Wo, 4 Wres, 5-20 W1, 21-36 W2. Block barriers only
// at the 3 cross-wave data points (merge, LN1/Xs, Hs). ----------
__global__ __launch_bounds__(512) void tail_kernel(
    const ushort_t* __restrict__ Opart, const float* __restrict__ Lst,
    const ushort_t* __restrict__ Wo,
    const ushort_t* __restrict__ Flt, const ushort_t* __restrict__ Wres,
    const float* __restrict__ g1, const float* __restrict__ bt1,
    const ushort_t* __restrict__ W1, const float* __restrict__ b1,
    const ushort_t* __restrict__ W2, const float* __restrict__ b2,
    const float* __restrict__ g2, const float* __restrict__ bt2,
    float* __restrict__ out) {
    __shared__ ushort_t Wb[3][16384];    // 96 KB ring; wave w touches only bytes [4096w,4096w+4096)
    __shared__ ushort_t As[16][264];
    __shared__ ushort_t Xs[16][264];
    __shared__ ushort_t Hs[16][1032];
    __shared__ ushort_t Fs[16][72];
    __shared__ float Bias[2304];
    __shared__ float redS[8][16], redQ[8][16];
    const int tid = threadIdx.x;
    const int wid = tid >> 6, lane = tid & 63;
    const int g = lane >> 4, r = lane & 15;
    const int row0 = blockIdx.x * 16;
    const int cw = wid * 32;

    // lane weight-frag byte offsets within a staged tile (all within wave's 4KB slice)
    const int wl00 = (cw + r) * 128 + ((g ^ (r & 7)) << 4);
    const int wl01 = wl00 + 2048;
    const int wl10 = (cw + r) * 128 + (((4 + g) ^ (r & 7)) << 4);
    const int wl11 = wl10 + 2048;

    // per-wave slice staging: wave w copies bytes [4096w, 4096w+4096) of the tile
    const int wslice = (wid << 12) + ((lane & 63) << 4);
    auto stageW = [&](const ushort_t* src, int buf) {
        const char* s = (const char*)src + wslice;
        char* d = (char*)&Wb[buf][0] + wslice;
#pragma unroll
        for (int j = 0; j < 4; ++j) {
            __builtin_amdgcn_global_load_lds(
                (const __attribute__((address_space(1))) unsigned int*)(s + j * 1024),
                (__attribute__((address_space(3))) unsigned int*)(d + j * 1024), 16, 0, 0);
        }
    };
    auto wsrc = [&](int s) -> const ushort_t* {
        if (s < 4)  return Wo + (size_t)s * 16384;
        if (s == 4) return Wres;
        if (s < 21) return W1 + (size_t)(s - 5) * 16384;
        return W2 + (size_t)(s - 21) * 16384;
    };

    // ---- phase A: merge SPLIT partials + pre-stage biases & Flt slice into LDS ----
    {
        const int ri = tid >> 5;
        const int cc = (tid & 31) << 3;
        const int h  = cc >> 5, d0 = cc & 31;
        const int n  = row0 + ri;
        float L = 0.f;
#pragma unroll
        for (int s = 0; s < SPLIT; ++s) L += Lst[(size_t)(s * NH + h) * NTOK + n];
        const float invL = 1.f / L;
        float o[8] = {0.f, 0.f, 0.f, 0.f, 0.f, 0.f, 0.f, 0.f};
#pragma unroll
        for (int s = 0; s < SPLIT; ++s) {
            const ushort_t* p = Opart + ((size_t)(s * NH + h) * NTOK + n) * HD + d0;
            const ushort4 a = *(const ushort4*)p;
            const ushort4 b = *(const ushort4*)(p + 4);
            o[0] += bf2f(a.x); o[1] += bf2f(a.y); o[2] += bf2f(a.z); o[3] += bf2f(a.w);
            o[4] += bf2f(b.x); o[5] += bf2f(b.y); o[6] += bf2f(b.z); o[7] += bf2f(b.w);
        }
        ushort4 m0, m1;
        m0.x = f2bf(o[0] * invL); m0.y = f2bf(o[1] * invL);
        m0.z = f2bf(o[2] * invL); m0.w = f2bf(o[3] * invL);
        m1.x = f2bf(o[4] * invL); m1.y = f2bf(o[5] * invL);
        m1.z = f2bf(o[6] * invL); m1.w = f2bf(o[7] * invL);
        *(ushort4*)&As[ri][cc]     = m0;
        *(ushort4*)&As[ri][cc + 4] = m1;
        *(ushort2*)&Fs[ri][(tid & 31) * 2] =
            *(const ushort2*)(Flt + (size_t)(row0 + ri) * C1 + (tid & 31) * 2);
#pragma unroll
        for (int i5 = 0; i5 < 5; ++i5) {
            const int i = i5 * 512 + tid;
            if (i < 2304) {
                float v;
                if      (i < 256)  v = g1[i];
                else if (i < 512)  v = bt1[i - 256];
                else if (i < 768)  v = b2[i - 512];
                else if (i < 1024) v = g2[i - 768];
                else if (i < 1280) v = bt2[i - 1024];
                else               v = b1[i - 1280];
                Bias[i] = v;
            }
        }
    }
    __syncthreads();   // As/Fs/Bias visible; also drains phase-A vmem

    // ---- ring prologue: per-wave depth-2 ----
    stageW(wsrc(0), 0);
    stageW(wsrc(1), 1);

    // ---- phase B: tiles 0..4 (Wo x4 + Wres), per-wave pipeline ----
    f32x4 accB[2] = {{0, 0, 0, 0}, {0, 0, 0, 0}};
#pragma unroll
    for (int t = 0; t < 5; ++t) {
        stageW(wsrc(t + 2), (t + 2) % 3);                 // t+2 <= 6 < 37 always
        asm volatile("s_waitcnt vmcnt(8)" ::: "memory");  // tile t ready (t+1,t+2 in flight)
        const char* wb = (const char*)&Wb[t % 3][0];
        const bf16x8 w00 = *(const bf16x8*)(wb + wl00);
        const bf16x8 w01 = *(const bf16x8*)(wb + wl01);
        const bf16x8 w10 = *(const bf16x8*)(wb + wl10);
        const bf16x8 w11 = *(const bf16x8*)(wb + wl11);
        bf16x8 af0, af1;
        if (t < 4) {
            af0 = *(const bf16x8*)&As[r][t * 64 + (g << 3)];
            af1 = *(const bf16x8*)&As[r][t * 64 + 32 + (g << 3)];
        } else {
            af0 = *(const bf16x8*)&Fs[r][(g << 3)];
            af1 = *(const bf16x8*)&Fs[r][32 + (g << 3)];
        }
        accB[0] = __builtin_amdgcn_mfma_f32_16x16x32_bf16(af0, w00, accB[0], 0, 0, 0);
        accB[1] = __builtin_amdgcn_mfma_f32_16x16x32_bf16(af0, w01, accB[1], 0, 0, 0);
        accB[0] = __builtin_amdgcn_mfma_f32_16x16x32_bf16(af1, w10, accB[0], 0, 0, 0);
        accB[1] = __builtin_amdgcn_mfma_f32_16x16x32_bf16(af1, w11, accB[1], 0, 0, 0);
    }
    // ---- LN1; xv stays in registers as FFN2 residual. (W1 prefetches keep flying.) ----
    f32x4 xv[2];
    {
        f32x4 sv, qv;
#pragma unroll
        for (int q = 0; q < 4; ++q) {
            float s = accB[0][q] + accB[1][q];
            float sq = fmaf(accB[0][q], accB[0][q], accB[1][q] * accB[1][q]);
            s += __shfl_xor(s, 1); s += __shfl_xor(s, 2); s += __shfl_xor(s, 4); s += __shfl_xor(s, 8);
            sq += __shfl_xor(sq, 1); sq += __shfl_xor(sq, 2); sq += __shfl_xor(sq, 4); sq += __shfl_xor(sq, 8);
            sv[q] = s; qv[q] = sq;
        }
        if (r == 0) { *(f32x4*)&redS[wid][4 * g] = sv; *(f32x4*)&redQ[wid][4 * g] = qv; }
        __syncthreads();
        f32x4 S = {0, 0, 0, 0}, SQ = {0, 0, 0, 0};
#pragma unroll
        for (int w = 0; w < 8; ++w) {
            S  += *(const f32x4*)&redS[w][4 * g];
            SQ += *(const f32x4*)&redQ[w][4 * g];
        }
        f32x4 mn4, rs4;
#pragma unroll
        for (int q = 0; q < 4; ++q) {
            mn4[q] = S[q] * (1.f / CF);
            rs4[q] = rsqrtf(fmaxf(SQ[q] * (1.f / CF) - mn4[q] * mn4[q], 0.f) + EPSF);
        }
#pragma unroll
        for (int t = 0; t < 2; ++t) {
            const int col = cw + 16 * t + r;
            const float gam = Bias[col], bet = Bias[256 + col];
#pragma unroll
            for (int q = 0; q < 4; ++q) {
                xv[t][q] = (accB[t][q] - mn4[q]) * rs4[q] * gam + bet;
                Xs[4 * g + q][col] = f2bf(xv[t][q]);
            }
        }
    }
    __syncthreads();   // Xs visible to all waves

    // ---- phase C: tiles 5..20 (W1), swapped MFMA, per-wave pipeline ----
    {
        f32x4 acc1[8];
#pragma unroll
        for (int t = 0; t < 8; ++t) acc1[t] = (f32x4){0, 0, 0, 0};
#pragma unroll
        for (int t = 5; t < 21; ++t) {
            stageW(wsrc(t + 2), (t + 2) % 3);             // t+2 <= 22 < 37 always
            asm volatile("s_waitcnt vmcnt(8)" ::: "memory");
            const int tc = t - 5;
            const char* wb = (const char*)&Wb[t % 3][0];
            const bf16x8 w00 = *(const bf16x8*)(wb + wl00);
            const bf16x8 w01 = *(const bf16x8*)(wb + wl01);
            const bf16x8 w10 = *(const bf16x8*)(wb + wl10);
            const bf16x8 w11 = *(const bf16x8*)(wb + wl11);
            const bf16x8 af0 = *(const bf16x8*)&Xs[r][(tc & 3) * 64 + (g << 3)];
            const bf16x8 af1 = *(const bf16x8*)&Xs[r][(tc & 3) * 64 + 32 + (g << 3)];
            const int idx = (tc >> 2) * 2;
            acc1[idx]     = __builtin_amdgcn_mfma_f32_16x16x32_bf16(w00, af0, acc1[idx], 0, 0, 0);
            acc1[idx + 1] = __builtin_amdgcn_mfma_f32_16x16x32_bf16(w01, af0, acc1[idx + 1], 0, 0, 0);
            acc1[idx]     = __builtin_amdgcn_mfma_f32_16x16x32_bf16(w10, af1, acc1[idx], 0, 0, 0);
            acc1[idx + 1] = __builtin_amdgcn_mfma_f32_16x16x32_bf16(w11, af1, acc1[idx + 1], 0, 0, 0);
        }
#pragma unroll
        for (int idx = 0; idx < 8; ++idx) {
            const int colb = (idx >> 1) * 256 + cw + 16 * (idx & 1) + 4 * g;
            const f32x4 bv = *(const f32x4*)&Bias[1280 + colb];
            ushort4 hw;
            hw.x = f2bf(fmaxf(acc1[idx][0] + bv[0], 0.f));
            hw.y = f2bf(fmaxf(acc1[idx][1] + bv[1], 0.f));
            hw.z = f2bf(fmaxf(acc1[idx][2] + bv[2], 0.f));
            hw.w = f2bf(fmaxf(acc1[idx][3] + bv[3], 0.f));
            *(ushort4*)&Hs[r][colb] = hw;
        }
    }
    __syncthreads();   // Hs visible to all waves (W2 prefetches keep flying)

    // ---- phase D: tiles 21..36 (W2, K=1024), per-wave pipeline ----
    f32x4 accD[2] = {{0, 0, 0, 0}, {0, 0, 0, 0}};
#pragma unroll
    for (int t = 21; t < 37; ++t) {
        if (t + 2 < 37) {
            stageW(wsrc(t + 2), (t + 2) % 3);
            asm volatile("s_waitcnt vmcnt(8)" ::: "memory");
        } else if (t + 1 < 37) {
            asm volatile("s_waitcnt vmcnt(4)" ::: "memory");
        } else {
            asm volatile("s_waitcnt vmcnt(0)" ::: "memory");
        }
        const int tc = t - 21;
        const char* wb = (const char*)&Wb[t % 3][0];
        const bf16x8 w00 = *(const bf16x8*)(wb + wl00);
        const bf16x8 w01 = *(const bf16x8*)(wb + wl01);
        const bf16x8 w10 = *(const bf16x8*)(wb + wl10);
        const bf16x8 w11 = *(const bf16x8*)(wb + wl11);
        const bf16x8 af0 = *(const bf16x8*)&Hs[r][tc * 64 + (g << 3)];
        const bf16x8 af1 = *(const bf16x8*)&Hs[r][tc * 64 + 32 + (g << 3)];
        accD[0] = __builtin_amdgcn_mfma_f32_16x16x32_bf16(af0, w00, accD[0], 0, 0, 0);
        accD[1] = __builtin_amdgcn_mfma_f32_16x16x32_bf16(af0, w01, accD[1], 0, 0, 0);
        accD[0] = __builtin_amdgcn_mfma_f32_16x16x32_bf16(af1, w10, accD[0], 0, 0, 0);
        accD[1] = __builtin_amdgcn_mfma_f32_16x16x32_bf16(af1, w11, accD[1], 0, 0, 0);
    }
    // ---- b2 + reg-residual + LN2 + transposed store ----
    {
#pragma unroll
        for (int t = 0; t < 2; ++t) {
            const float bb = Bias[512 + cw + 16 * t + r];
#pragma unroll
            for (int q = 0; q < 4; ++q) accD[t][q] += bb + xv[t][q];
        }
        f32x4 sv, qv;
#pragma unroll
        for (int q = 0; q < 4; ++q) {
            float s = accD[0][q] + accD[1][q];
            float sq = fmaf(accD[0][q], accD[0][q], accD[1][q] * accD[1][q]);
            s += __shfl_xor(s, 1); s += __shfl_xor(s, 2); s += __shfl_xor(s, 4); s += __shfl_xor(s, 8);
            sq += __shfl_xor(sq, 1); sq += __shfl_xor(sq, 2); sq += __shfl_xor(sq, 4); sq += __shfl_xor(sq, 8);
            sv[q] = s; qv[q] = sq;
        }
        __syncthreads();   // redS/redQ from LN1 fully consumed; safe to reuse
        if (r == 0) { *(f32x4*)&redS[wid][4 * g] = sv; *(f32x4*)&redQ[wid][4 * g] = qv; }
        __syncthreads();
        f32x4 S = {0, 0, 0, 0}, SQ = {0, 0, 0, 0};
#pragma unroll
        for (int w = 0; w < 8; ++w) {
            S  += *(const f32x4*)&redS[w][4 * g];
            SQ += *(const f32x4*)&redQ[w][4 * g];
        }
        f32x4 mn4, rs4;
#pragma unroll
        for (int q = 0; q < 4; ++q) {
            mn4[q] = S[q] * (1.f / CF);
            rs4[q] = rsqrtf(fmaxf(SQ[q] * (1.f / CF) - mn4[q] * mn4[q], 0.f) + EPSF);
        }
#pragma unroll
        for (int t = 0; t < 2; ++t) {
            const int col = cw + 16 * t + r;
            const float gam = Bias[768 + col], bet = Bias[1024 + col];
            f32x4 ov;
#pragma unroll
            for (int q = 0; q < 4; ++q)
                ov[q] = (accD[t][q] - mn4[q]) * rs4[q] * gam + bet;
            *(f32x4*)(out + (size_t)col * NTOK + row0 + 4 * g) = ov;
        }
    }
}

extern "C" void kernel_launch(void* const* d_in, const int* in_sizes, int n_in,
                              void* d_out, int out_size, void* d_ws, size_t ws_size,
                              hipStream_t stream) {
    const float* F_lidar = (const float*)d_in[0];
    const float* F_cam   = (const float*)d_in[1];
    const float* Wq      = (const float*)d_in[2];
    const float* Wk      = (const float*)d_in[3];
    const float* Wv      = (const float*)d_in[4];
    const float* Wo      = (const float*)d_in[5];
    const float* Wres    = (const float*)d_in[6];
    const float* ln1_g   = (const float*)d_in[7];
    const float* ln1_b   = (const float*)d_in[8];
    const float* ln2_g   = (const float*)d_in[9];
    const float* ln2_b   = (const float*)d_in[10];
    const float* W1      = (const float*)d_in[11];
    const float* b1      = (const float*)d_in[12];
    const float* W2      = (const float*)d_in[13];
    const float* b2      = (const float*)d_in[14];
    float* out = (float*)d_out;
    char* ws = (char*)d_ws;

    const size_t KB = 1024, MB = 1024 * 1024;
    ushort_t* Wq_b   = (ushort_t*)(ws + 0);
    ushort_t* Wk_b   = (ushort_t*)(ws + 32 * KB);
    ushort_t* Wv_b   = (ushort_t*)(ws + 160 * KB);
    ushort_t* Wo_b   = (ushort_t*)(ws + 288 * KB);
    ushort_t* Wres_b = (ushort_t*)(ws + 416 * KB);
    ushort_t* W1_b   = (ushort_t*)(ws + 448 * KB);
    ushort_t* W2_b   = (ushort_t*)(ws + 960 * KB);
    ushort_t* Flt    = (ushort_t*)(ws + 1536 * KB);   // bf16 [4096][64]
    ushort_t* Fct    = (ushort_t*)(ws + 2 * MB);      // bf16 [4096][256]
    ushort_t* Qb     = (ushort_t*)(ws + 4 * MB);      // 2 MB (pre-scaled)
    ushort_t* Kb     = (ushort_t*)(ws + 6 * MB);      // 2 MB (bank-swizzled dims)
    ushort_t* Vt     = (ushort_t*)(ws + 8 * MB);      // 2 MB (unit layout per head/tile)
    ushort_t* Opart  = (ushort_t*)(ws + 12 * MB);     // 8 MB bf16 [4][8][4096][32]
    float*    Lst    = (float*)(ws + 20 * MB);        // 512 KB

    prep_kernel<<<2016, 256, 0, stream>>>(Wq, Wk, Wv, Wo, Wres, W1, W2, F_lidar, F_cam,
                                          Wq_b, Wk_b, Wv_b, Wo_b, Wres_b, W1_b, W2_b, Flt, Fct);
    qkv_kernel<<<dim3(NTOK / 128, CF / 64, 3), 256, 0, stream>>>(Flt, Fct, Wq_b, Wk_b, Wv_b, Qb, Kb, Vt);
    fattn_kernel<<<NH * SPLIT * (NTOK / 256), 512, 0, stream>>>(Qb, Kb, Vt, Opart, Lst);
    tail_kernel<<<NTOK / 16, 512, 0, stream>>>(Opart, Lst, Wo_b, Flt, Wres_b, ln1_g, ln1_b,
                                               W1_b, b1, W2_b, b2, ln2_g, ln2_b, out);
}